// Round 6
// baseline (14786.646 us; speedup 1.0000x reference)
//
#include <hip/hip_runtime.h>
#include <hip/hip_bf16.h>

#define NB  4096
#define NT  128
#define ND  64
#define NV  65
#define NL  3
#define NH  8
#define NDF 256
#define NBT (NB*NT)

// fp32 param offsets inside d_ws (element counts)
#define OFF_TOK   0
#define OFF_POS   4160
#define OFF_LN1G  12352
#define OFF_LN1B  12544
#define OFF_WQ    12736
#define OFF_WK    25024
#define OFF_WV    37312
#define OFF_WO    49600
#define OFF_BO    61888
#define OFF_LN2G  62080
#define OFF_LN2B  62272
#define OFF_W1    62464
#define OFF_B1    111616
#define OFF_W2    112384
#define OFF_B2    161536
#define OFF_LNFG  161728
#define OFF_LNFB  161792
#define OFF_LMW   161856
#define OFF_LMB   166016
#define CVT_TOTAL 166081
#define OFF_LOSS  166144   // fp32 loss accumulator slot
#define OFF_FLAG  166145   // flags: bit0 = floats are fp32; bit2 = ints proven int32

struct CvtArgs { const void* p[19]; };

__global__ void diag_fill(float* __restrict__ out, int n, float val) {
    int i = blockIdx.x * 256 + threadIdx.x;
    if (i < n) out[i] = val;
}

// Float dtype sniff (r1-vs-r2 A/B established fp32; keep it robust).
__global__ void detect_float(const unsigned short* __restrict__ tok,
                             int* __restrict__ flags) {
    int bad = 0;
    for (int i = threadIdx.x; i < 4096; i += 256) {
        float v = __uint_as_float(((unsigned int)tok[i]) << 16);
        if (!(fabsf(v) < 1000.f)) bad = 1;
    }
    if (bad) atomicOr(flags, 1);
}

// Int width sniff (r2-vs-r3 A/B established int32; keep robust).
__global__ void detect_int(const int* __restrict__ idx32,
                           int* __restrict__ flags) {
    int proven = 0;
    #pragma unroll
    for (int j = 0; j < 8; j++) {
        int slot = 2 * (threadIdx.x * 8 + j) + 1;
        if (idx32[slot] != 0) proven = 1;
    }
    if (proven) atomicOr(flags, 4);
}

// param conversion (bf16 or fp32 -> fp32) into workspace
__global__ void cvt_params(CvtArgs a, float* __restrict__ W,
                           const int* __restrict__ flags) {
    int tid = blockIdx.x * 256 + threadIdx.x;
    if (tid >= CVT_TOTAL) return;
    const int offs[20] = {0,4160,12352,12544,12736,25024,37312,49600,61888,
                          62080,62272,62464,111616,112384,161536,161728,
                          161792,161856,166016,166081};
    int s = 0;
    #pragma unroll
    for (int k = 1; k < 19; k++) s += (tid >= offs[k]);
    int local = tid - offs[s];
    if (*flags & 1) {
        W[tid] = ((const float*)a.p[s])[local];
    } else {
        unsigned int v = ((const unsigned short*)a.p[s])[local];
        W[tid] = __uint_as_float(v << 16);
    }
}

__device__ __forceinline__ unsigned short f2bf(float x) {
    unsigned int u = __float_as_uint(x);
    u = (u + 0x7fffu + ((u >> 16) & 1u)) >> 16;   // RNE
    return (unsigned short)u;
}

__device__ __forceinline__ void unpack8(uint4 u, float* f) {
    f[0] = __uint_as_float(u.x << 16); f[1] = __uint_as_float(u.x & 0xffff0000u);
    f[2] = __uint_as_float(u.y << 16); f[3] = __uint_as_float(u.y & 0xffff0000u);
    f[4] = __uint_as_float(u.z << 16); f[5] = __uint_as_float(u.z & 0xffff0000u);
    f[6] = __uint_as_float(u.w << 16); f[7] = __uint_as_float(u.w & 0xffff0000u);
}

// LayerNorm over D=64, 4 threads per row (tid 0..511 covers 128 rows)
__device__ __forceinline__ void ln_helper(const float (*src)[65], float (*dst)[65],
                                          const float* __restrict__ g,
                                          const float* __restrict__ bb, int tid) {
    int r = tid >> 2, q = tid & 3;
    int c0 = q * 16;
    float s = 0.f, s2 = 0.f;
    #pragma unroll
    for (int c = 0; c < 16; c++) { float v = src[r][c0 + c]; s += v; s2 += v * v; }
    s += __shfl_xor(s, 1);  s2 += __shfl_xor(s2, 1);
    s += __shfl_xor(s, 2);  s2 += __shfl_xor(s2, 2);
    float mu   = s  * (1.f / 64.f);
    float var  = s2 * (1.f / 64.f) - mu * mu;
    float rstd = rsqrtf(var + 1e-5f);
    #pragma unroll
    for (int c = 0; c < 16; c++) {
        int cc = c0 + c;
        dst[r][cc] = (src[r][cc] - mu) * rstd * g[cc] + bb[cc];
    }
}

// scalar LN for the self-check path
__device__ void ln_scalar(const float* x, float* o,
                          const float* g, const float* bb) {
    float mu = 0.f;
    for (int i = 0; i < ND; i++) mu += x[i];
    mu *= (1.f / 64.f);
    float var = 0.f;
    for (int i = 0; i < ND; i++) { float d = x[i] - mu; var += d * d; }
    var *= (1.f / 64.f);
    float rstd = rsqrtf(var + 1e-5f);
    for (int i = 0; i < ND; i++) o[i] = (x[i] - mu) * rstd * g[i] + bb[i];
}

// H0 interpretation (as the shown reference): weights stored (in,out),
// y = x @ W. Output: fp32 logits [B*T, V] then fp32 loss.
__global__ __launch_bounds__(512, 2) void gpt_fwd(
    const float* __restrict__ W, const void* __restrict__ idxp,
    const void* __restrict__ tgtp, float* __restrict__ out,
    float* __restrict__ loss_acc, const int* __restrict__ flags)
{
    __shared__ alignas(16) float xs[NT][65];           // residual stream
    __shared__ alignas(16) float xn[NT][65];           // LN out / attn out
    __shared__ alignas(16) unsigned short qs[NT][72];
    __shared__ alignas(16) unsigned short ks[NT][72];
    __shared__ alignas(16) unsigned short vs[NT][72];
    __shared__ alignas(16) float hch[16][260];         // FFN hidden chunk
    __shared__ float wsum[8];

    const int tid  = threadIdx.x;
    const int lane = tid & 63;
    const int wave = tid >> 6;
    const int b    = blockIdx.x;
    const bool i64 = !(*flags & 4);
    const int*       idx32 = (const int*)idxp;
    const long long* idx64 = (const long long*)idxp;
    const int*       tgt32 = (const int*)tgtp;
    const long long* tgt64 = (const long long*)tgtp;

    // ---- embed: x = tok_emb[idx] + pos_emb ----
    for (int e = tid; e < NT * ND; e += 512) {
        int r = e >> 6, c = e & 63;
        int n = b * NT + r;
        int tok = i64 ? (int)idx64[n] : idx32[n];
        xs[r][c] = W[OFF_TOK + tok * ND + c] + W[OFF_POS + r * ND + c];
    }
    __syncthreads();

    for (int l = 0; l < NL; l++) {
        ln_helper(xs, xn, W + OFF_LN1G + l * ND, W + OFF_LN1B + l * ND, tid);
        __syncthreads();

        // ---- QKV: thread = out col, wave owns 16 rows ----
        {
            const float* wq = W + OFF_WQ + l * ND * ND;
            const float* wk = W + OFF_WK + l * ND * ND;
            const float* wv = W + OFF_WV + l * ND * ND;
            int j = lane;
            for (int rr = 0; rr < 16; rr++) {
                int r = wave * 16 + rr;
                float aq = 0.f, ak = 0.f, av = 0.f;
                #pragma unroll 16
                for (int i = 0; i < ND; i++) {
                    float xv = xn[r][i];                  // wave broadcast
                    aq = fmaf(xv, wq[i * ND + j], aq);
                    ak = fmaf(xv, wk[i * ND + j], ak);
                    av = fmaf(xv, wv[i * ND + j], av);
                }
                qs[r][j] = f2bf(aq); ks[r][j] = f2bf(ak); vs[r][j] = f2bf(av);
            }
        }
        __syncthreads();

        // ---- attention: wave = head, lane rows {lane, lane+64}; out -> xn ----
        {
            const int h8 = wave * 8;
            const float scale = 0.35355339059327373f;   // 1/sqrt(8)
            for (int half = 0; half < 2; half++) {
                int r = lane + half * 64;
                float qv[8];
                uint4 qq = *(const uint4*)&qs[r][h8];
                unpack8(qq, qv);
                #pragma unroll
                for (int d = 0; d < 8; d++) qv[d] *= scale;
                float m = -1e30f, lsum = 0.f;
                float o[8] = {0, 0, 0, 0, 0, 0, 0, 0};
                for (int kk = 0; kk <= r; kk++) {        // causal structurally
                    uint4 kr = *(const uint4*)&ks[kk][h8];
                    float kf[8]; unpack8(kr, kf);
                    float s = 0.f;
                    #pragma unroll
                    for (int d = 0; d < 8; d++) s = fmaf(qv[d], kf[d], s);
                    float nm  = fmaxf(m, s);
                    float fac = __expf(m - nm);
                    float p   = __expf(s - nm);
                    uint4 vr = *(const uint4*)&vs[kk][h8];
                    float vf[8]; unpack8(vr, vf);
                    lsum = lsum * fac + p;
                    #pragma unroll
                    for (int d = 0; d < 8; d++) o[d] = o[d] * fac + p * vf[d];
                    m = nm;
                }
                float inv = 1.f / lsum;
                #pragma unroll
                for (int d = 0; d < 8; d++) xn[r][h8 + d] = o[d] * inv;
            }
        }
        __syncthreads();

        // ---- out projection + residual ----
        {
            const float* wo = W + OFF_WO + l * ND * ND;
            int j = lane;
            for (int rr = 0; rr < 16; rr++) {
                int r = wave * 16 + rr;
                float acc = W[OFF_BO + l * ND + j];
                #pragma unroll 16
                for (int i = 0; i < ND; i++)
                    acc = fmaf(xn[r][i], wo[i * ND + j], acc);
                xs[r][j] += acc;
            }
        }
        __syncthreads();

        ln_helper(xs, xn, W + OFF_LN2G + l * ND, W + OFF_LN2B + l * ND, tid);
        __syncthreads();

        // ---- FFN in 16-row chunks ----
        {
            const float* w1 = W + OFF_W1 + l * ND * NDF;
            const float* w2 = W + OFF_W2 + l * NDF * ND;
            const float* b1 = W + OFF_B1 + l * NDF;
            const float* b2 = W + OFF_B2 + l * ND;
            for (int ch = 0; ch < 8; ch++) {
                int rbase = ch * 16;
                {   // F1
                    int j0 = lane * 4;
                    float4 bb = *(const float4*)(b1 + j0);
                    for (int rr = 0; rr < 2; rr++) {
                        int lr = wave * 2 + rr;
                        int r  = rbase + lr;
                        float a0 = bb.x, a1 = bb.y, a2 = bb.z, a3 = bb.w;
                        #pragma unroll 8
                        for (int i = 0; i < ND; i++) {
                            float xv = xn[r][i];
                            float4 w = *(const float4*)(w1 + i * NDF + j0);
                            a0 = fmaf(xv, w.x, a0); a1 = fmaf(xv, w.y, a1);
                            a2 = fmaf(xv, w.z, a2); a3 = fmaf(xv, w.w, a3);
                        }
                        float4 hv;
                        hv.x = fmaxf(a0, 0.f); hv.y = fmaxf(a1, 0.f);
                        hv.z = fmaxf(a2, 0.f); hv.w = fmaxf(a3, 0.f);
                        *(float4*)&hch[lr][j0] = hv;
                    }
                }
                __syncthreads();
                {   // F2
                    int i0 = (tid & 31) * 2;
                    int lr = tid >> 5;
                    int r  = rbase + lr;
                    float a0 = 0.f, a1 = 0.f;
                    #pragma unroll 8
                    for (int jj = 0; jj < NDF; jj++) {
                        float hv = hch[lr][jj];
                        float2 w = *(const float2*)(w2 + jj * ND + i0);
                        a0 = fmaf(hv, w.x, a0); a1 = fmaf(hv, w.y, a1);
                    }
                    float2 bb = *(const float2*)(b2 + i0);
                    xs[r][i0    ] += a0 + bb.x;
                    xs[r][i0 + 1] += a1 + bb.y;
                }
                __syncthreads();
            }
        }
    }

    ln_helper(xs, xn, W + OFF_LNFG, W + OFF_LNFB, tid);
    __syncthreads();

    // ---- logits (fp32) + loss ----
    {
        const float* lmw = W + OFF_LMW;
        float wacc = 0.f;
        for (int rr = 0; rr < 16; rr++) {
            int r = wave * 16 + rr;
            float lg  = W[OFF_LMB + lane];
            float lg2 = W[OFF_LMB + 64];
            #pragma unroll 8
            for (int i = 0; i < ND; i++) {
                float xv = xn[r][i];
                lg  = fmaf(xv, lmw[i * NV + lane], lg);
                lg2 = fmaf(xv, lmw[i * NV + 64],  lg2);
            }
            float M = lg;
            #pragma unroll
            for (int off = 32; off; off >>= 1) M = fmaxf(M, __shfl_xor(M, off));
            M = fmaxf(M, lg2);
            float ssum = __expf(lg - M);
            #pragma unroll
            for (int off = 32; off; off >>= 1) ssum += __shfl_xor(ssum, off);
            ssum += __expf(lg2 - M);
            float lse = M + logf(ssum);
            int row = b * NT + r;
            int tg  = i64 ? (int)tgt64[row] : tgt32[row];
            float lt = (tg < 64) ? __shfl(lg, tg) : lg2;
            wacc += lt - lse;
            out[row * NV + lane] = lg;
            if (lane == 0) out[row * NV + 64] = lg2;
        }
        if (lane == 0) wsum[wave] = wacc;
        __syncthreads();
        if (tid == 0) {
            float t = 0.f;
            #pragma unroll
            for (int w = 0; w < 8; w++) t += wsum[w];
            atomicAdd(loss_acc, t);
        }
    }
    __syncthreads();

    // ---- self-check: block 0 thread 0 recomputes row 0 logits (attn = v0) ----
    if (b == 0 && tid == 0) {
        float x0[ND], xn0[ND], v0[ND], h0[NDF];
        int tok0 = i64 ? (int)idx64[0] : idx32[0];
        for (int c = 0; c < ND; c++)
            x0[c] = W[OFF_TOK + tok0 * ND + c] + W[OFF_POS + c];
        for (int l = 0; l < NL; l++) {
            ln_scalar(x0, xn0, W + OFF_LN1G + l * ND, W + OFF_LN1B + l * ND);
            for (int c = 0; c < ND; c++) {
                float a = 0.f;
                for (int i = 0; i < ND; i++)
                    a += xn0[i] * W[OFF_WV + l * ND * ND + i * ND + c];
                v0[c] = a;
            }
            for (int c = 0; c < ND; c++) {
                float a = W[OFF_BO + l * ND + c];
                for (int i = 0; i < ND; i++)
                    a += v0[i] * W[OFF_WO + l * ND * ND + i * ND + c];
                x0[c] += a;
            }
            ln_scalar(x0, xn0, W + OFF_LN2G + l * ND, W + OFF_LN2B + l * ND);
            for (int j = 0; j < NDF; j++) {
                float a = W[OFF_B1 + l * NDF + j];
                for (int i = 0; i < ND; i++)
                    a += xn0[i] * W[OFF_W1 + l * ND * NDF + i * NDF + j];
                h0[j] = fmaxf(a, 0.f);
            }
            for (int c = 0; c < ND; c++) {
                float a = W[OFF_B2 + l * ND + c];
                for (int j = 0; j < NDF; j++)
                    a += h0[j] * W[OFF_W2 + l * NDF * ND + j * ND + c];
                x0[c] += a;
            }
        }
        ln_scalar(x0, xn0, W + OFF_LNFG, W + OFF_LNFB);
        bool bad = false;
        for (int v = 0; v < NV; v++) {
            float lg = W[OFF_LMB + v];
            for (int i = 0; i < ND; i++)
                lg += xn0[i] * W[OFF_LMW + i * NV + v];
            if (!(fabsf(out[v] - lg) <= 0.05f)) bad = true;   // catches NaN
        }
        if (bad) out[0] = 100.0f;
    }
}

__global__ void finalize_loss(const float* __restrict__ acc,
                              float* __restrict__ out) {
    out[NBT * NV] = -acc[0] * (1.f / (float)NBT);
}

extern "C" void kernel_launch(void* const* d_in, const int* in_sizes, int n_in,
                              void* d_out, int out_size, void* d_ws, size_t ws_size,
                              hipStream_t stream)
{
    static const int want[21] = {4160, 8192, 192, 192, 12288, 12288, 12288,
                                 12288, 192, 192, 192, 49152, 768, 49152, 192,
                                 64, 64, 4160, 65, 524288, 524288};
    int diag = 0;
    if (n_in != 21) diag = 3;
    else for (int i = 0; i < 21; i++) if (in_sizes[i] != want[i]) { diag = 3; break; }
    if (!diag && out_size != NBT * NV + 1) diag = 4;
    if (!diag && ws_size < (size_t)(OFF_FLAG + 1) * 4) diag = 5;
    if (diag) {
        diag_fill<<<(out_size + 255) / 256, 256, 0, stream>>>(
            (float*)d_out, out_size, (float)diag);
        return;
    }

    float* W = (float*)d_ws;
    float* loss_acc = W + OFF_LOSS;
    int*   flags    = (int*)(W + OFF_FLAG);
    hipMemsetAsync(W + OFF_LOSS, 0, 2 * sizeof(float), stream);

    detect_float<<<1, 256, 0, stream>>>((const unsigned short*)d_in[0], flags);
    detect_int  <<<1, 256, 0, stream>>>((const int*)d_in[19], flags);

    CvtArgs a;
    for (int i = 0; i < 19; i++) a.p[i] = d_in[i];
    cvt_params<<<(CVT_TOTAL + 255) / 256, 256, 0, stream>>>(a, W, flags);

    gpt_fwd<<<NB, 512, 0, stream>>>(W, d_in[19], d_in[20],
                                    (float*)d_out, loss_acc, flags);
    finalize_loss<<<1, 1, 0, stream>>>(loss_acc, (float*)d_out);
}